// Round 12
// baseline (54.718 us; speedup 1.0000x reference)
//
#include <hip/hip_runtime.h>
#include <math.h>

#define KLEN 512
#define QLEN 64
#define ADIM 512
#define BATCH 4
#define NH 4

typedef __attribute__((ext_vector_type(8))) short bf16x8;
typedef __attribute__((ext_vector_type(4))) float f32x4;
typedef _Float16 f16;
typedef __attribute__((ext_vector_type(2))) _Float16 f16x2;

__device__ __forceinline__ f16x2 u2h(unsigned int u) {
  union { unsigned int u; f16x2 h; } v; v.u = u; return v.h;
}

// Pack float4 -> 4 bf16 (short4) by truncation (RTZ): one v_perm_b32 per pair.
__device__ __forceinline__ short4 pack4(float4 x) {
  union { unsigned int u[2]; short4 s; } o;
  o.u[0] = __builtin_amdgcn_perm(__float_as_uint(x.y), __float_as_uint(x.x), 0x07060302);
  o.u[1] = __builtin_amdgcn_perm(__float_as_uint(x.w), __float_as_uint(x.z), 0x07060302);
  return o.s;
}

// ---------------------------------------------------------------------------
// proj_mfma — BYTE-IDENTICAL to round 10 (measurement control).
// ---------------------------------------------------------------------------
__global__ __launch_bounds__(512) void proj_mfma(
    const float* __restrict__ key, const float* __restrict__ query,
    const float* __restrict__ wk, const float* __restrict__ bk,
    const float* __restrict__ wq,
    const float* __restrict__ v_v, const float* __restrict__ v_g,
    f16* __restrict__ Kp, f16* __restrict__ Qp, f16* __restrict__ Wn) {
  __shared__ short At[2][64 * 40];
  __shared__ short Wt[2][64 * 40];

  const int bid = blockIdx.x;
  const int tid = threadIdx.x;

  if (bid == 288) {  // ---- wnorm (512 threads: 1 elem each) ----
    __shared__ float wred[512];
    for (int h = 0; h < NH; ++h) {
      float v0 = v_v[h * ADIM + tid];
      wred[tid] = v0 * v0;
      __syncthreads();
      for (int s2 = 256; s2 > 0; s2 >>= 1) {
        if (tid < s2) wred[tid] += wred[tid + s2];
        __syncthreads();
      }
      float scale = v_g[h] / sqrtf(wred[0]);
      Wn[h * ADIM + tid] = (f16)(v0 * scale);
      __syncthreads();
    }
    return;
  }

  const float *A, *W, *bias;
  f16* C;
  int m0, a0;
  if (bid < 256) {
    A = key; W = wk; bias = bk; C = Kp;
    m0 = (bid >> 3) * 64; a0 = (bid & 7) * 64;
  } else {
    const int t = bid - 256;
    A = query; W = wq; bias = nullptr; C = Qp;
    m0 = (t >> 3) * 64; a0 = (t & 7) * 64;
  }

  const int w = tid >> 6;
  const int wr = w >> 2;          // 0..1 (32 m-rows each)
  const int wc = w & 3;           // 0..3 (16 n-cols each)
  const int lane = tid & 63;
  const int lr = lane & 15, hi = lane >> 4;
  const int srow = tid >> 3;      // staging row 0..63
  const int scol = (tid & 7) * 4; // staging f32 col 0..28

  const float* Arow = &A[(size_t)(m0 + srow) * ADIM + scol];
  const float* Wrow = &W[(size_t)(a0 + srow) * ADIM + scol];

  f32x4 acc0 = {0.f, 0.f, 0.f, 0.f};
  f32x4 acc1 = {0.f, 0.f, 0.f, 0.f};

  {  // prologue: chunk 0 -> buf 0
    float4 fa = *(const float4*)&Arow[0];
    float4 fw = *(const float4*)&Wrow[0];
    *(short4*)&At[0][srow * 40 + scol] = pack4(fa);
    *(short4*)&Wt[0][srow * 40 + scol] = pack4(fw);
  }
  __syncthreads();

  for (int c = 0; c < 16; ++c) {
    float4 na, nw;
    if (c < 15) {
      na = *(const float4*)&Arow[(c + 1) * 32];
      nw = *(const float4*)&Wrow[(c + 1) * 32];
    }
    const short* Ab = At[c & 1];
    const short* Wb = Wt[c & 1];
    bf16x8 af0 = *(const bf16x8*)&Ab[(wr * 32 + lr) * 40 + hi * 8];
    bf16x8 af1 = *(const bf16x8*)&Ab[(wr * 32 + 16 + lr) * 40 + hi * 8];
    bf16x8 wf  = *(const bf16x8*)&Wb[(wc * 16 + lr) * 40 + hi * 8];
    acc0 = __builtin_amdgcn_mfma_f32_16x16x32_bf16(af0, wf, acc0, 0, 0, 0);
    acc1 = __builtin_amdgcn_mfma_f32_16x16x32_bf16(af1, wf, acc1, 0, 0, 0);
    if (c < 15) {
      *(short4*)&At[(c + 1) & 1][srow * 40 + scol] = pack4(na);
      *(short4*)&Wt[(c + 1) & 1][srow * 40 + scol] = pack4(nw);
    }
    __syncthreads();
  }

  const int ccol = a0 + wc * 16 + lr;
  const float bv = bias ? bias[ccol] : 0.f;
#pragma unroll
  for (int i = 0; i < 4; ++i) {
    const int crow0 = m0 + wr * 32 + hi * 4 + i;
    C[(size_t)crow0 * ADIM + ccol] = (f16)(acc0[i] + bv);
    C[(size_t)(crow0 + 16) * ADIM + ccol] = (f16)(acc1[i] + bv);
  }
}

// ---------------------------------------------------------------------------
// energy — BYTE-IDENTICAL to round 10. Launched 4x (idempotent: reads only
// Kp/Qp/Wn/mask/r, writes every out element deterministically) to measure
// its time: E = (total_r12 - total_r10)/3.
// ---------------------------------------------------------------------------
__global__ __launch_bounds__(256) void energy_kernel(
    const f16* __restrict__ Kp, const f16* __restrict__ Qp,
    const f16* __restrict__ Wn, const int* __restrict__ mask,
    const float* __restrict__ r, float* __restrict__ out) {
  __shared__ f16 Kl[16 * 520];
  __shared__ f16 Ql[16 * 520];
  __shared__ float Red[2][1280];  // [wavepair][cell*5 + n]

  const int b = blockIdx.z;
  const int q0 = blockIdx.y * 16;
  const int kl0 = blockIdx.x * 16;
  const int tid = threadIdx.x;
  const int wave = tid >> 6;
  const int lane = tid & 63;
  const int klg = lane & 7;
  const int qg = lane >> 3;

  const float rv = r[0];

  const unsigned short* Kb = (const unsigned short*)(Kp + ((size_t)b * KLEN + kl0) * ADIM);
  const unsigned short* Qb = (const unsigned short*)(Qp + ((size_t)b * QLEN + q0) * ADIM);

  const unsigned int* Wd = (const unsigned int*)Wn;  // [4][256] dwords
  uint4 wreg = *(const uint4*)&Wd[(lane >> 4) * 256 + wave * 64 + (lane & 15) * 4];

#pragma unroll
  for (int j = 0; j < 4; ++j) {
    const int u = tid + 256 * j;
    const int row = u >> 6, c8 = (u & 63) * 8;
    *(uint4*)&Kl[row * 520 + c8] = *(const uint4*)&Kb[row * ADIM + c8];
    *(uint4*)&Ql[row * 520 + c8] = *(const uint4*)&Qb[row * ADIM + c8];
  }
  __syncthreads();

  float acc[2][2][4] = {};  // [kl-half][q-half][n]
  const int abase = wave * 128;

#pragma unroll
  for (int s = 0; s < 16; ++s) {
    const int off = abase + s * 8;
    uint4 ka = *(const uint4*)&Kl[klg * 520 + off];
    uint4 kb = *(const uint4*)&Kl[(klg + 8) * 520 + off];
    uint4 qa = *(const uint4*)&Ql[qg * 520 + off];
    uint4 qb = *(const uint4*)&Ql[(qg + 8) * 520 + off];
    unsigned wdw[4][4];
#pragma unroll
    for (int n = 0; n < 4; ++n) {
      wdw[n][0] = (unsigned)__builtin_amdgcn_readlane((int)wreg.x, n * 16 + s);
      wdw[n][1] = (unsigned)__builtin_amdgcn_readlane((int)wreg.y, n * 16 + s);
      wdw[n][2] = (unsigned)__builtin_amdgcn_readlane((int)wreg.z, n * 16 + s);
      wdw[n][3] = (unsigned)__builtin_amdgcn_readlane((int)wreg.w, n * 16 + s);
    }
    unsigned ks[2][4] = {{ka.x, ka.y, ka.z, ka.w}, {kb.x, kb.y, kb.z, kb.w}};
    unsigned qs[2][4] = {{qa.x, qa.y, qa.z, qa.w}, {qb.x, qb.y, qb.z, qb.w}};
#pragma unroll
    for (int j = 0; j < 4; ++j) {
      const f16x2 wv0 = u2h(wdw[0][j]), wv1 = u2h(wdw[1][j]);
      const f16x2 wv2 = u2h(wdw[2][j]), wv3 = u2h(wdw[3][j]);
#pragma unroll
      for (int ki = 0; ki < 2; ++ki) {
        const f16x2 kv = u2h(ks[ki][j]);
#pragma unroll
        for (int qi = 0; qi < 2; ++qi) {
          f16x2 sum = kv + u2h(qs[qi][j]);
          f16x2 rl = __builtin_elementwise_max(sum, (f16x2)(_Float16)0);
          acc[ki][qi][0] = __builtin_amdgcn_fdot2(rl, wv0, acc[ki][qi][0], false);
          acc[ki][qi][1] = __builtin_amdgcn_fdot2(rl, wv1, acc[ki][qi][1], false);
          acc[ki][qi][2] = __builtin_amdgcn_fdot2(rl, wv2, acc[ki][qi][2], false);
          acc[ki][qi][3] = __builtin_amdgcn_fdot2(rl, wv3, acc[ki][qi][3], false);
        }
      }
    }
  }

  const int half = wave & 1;
  if (wave < 2) {
#pragma unroll
    for (int ki = 0; ki < 2; ++ki)
#pragma unroll
      for (int qi = 0; qi < 2; ++qi) {
        const int cell = (qg + 8 * qi) * 16 + klg + 8 * ki;
#pragma unroll
        for (int n = 0; n < 4; ++n) Red[half][cell * 5 + n] = acc[ki][qi][n];
      }
  }
  __syncthreads();
  if (wave >= 2) {
#pragma unroll
    for (int ki = 0; ki < 2; ++ki)
#pragma unroll
      for (int qi = 0; qi < 2; ++qi) {
        const int cell = (qg + 8 * qi) * 16 + klg + 8 * ki;
#pragma unroll
        for (int n = 0; n < 4; ++n) Red[half][cell * 5 + n] += acc[ki][qi][n];
      }
  }
  __syncthreads();

  const float NEG_BIG = __uint_as_float(0xFF7F0000u);  // finite under bf16 cast
  const int n = tid >> 6;
  const int q = (tid >> 2) & 15;
  const int klb = (tid & 3) * 4;
  const int4 mv = *(const int4*)&mask[((size_t)b * QLEN + q0 + q) * KLEN + kl0 + klb];
  const int mm[4] = {mv.x, mv.y, mv.z, mv.w};
  float4 o;
  float* op = &o.x;
#pragma unroll
  for (int t = 0; t < 4; ++t) {
    const int cell = q * 16 + klb + t;
    float v = Red[0][cell * 5 + n] + Red[1][cell * 5 + n] + rv;
    op[t] = mm[t] ? v : NEG_BIG;
  }
  *(float4*)&out[(((size_t)b * NH + n) * QLEN + q0 + q) * KLEN + kl0 + klb] = o;
}

extern "C" void kernel_launch(void* const* d_in, const int* in_sizes, int n_in,
                              void* d_out, int out_size, void* d_ws, size_t ws_size,
                              hipStream_t stream) {
  const float* key   = (const float*)d_in[0];  // [4,512,512] f32
  const float* query = (const float*)d_in[1];  // [4,64,512]  f32
  const int*   mask  = (const int*)d_in[2];    // [4,64,512]  i32
  const float* wk    = (const float*)d_in[3];  // [512,512]   f32
  const float* bk    = (const float*)d_in[4];  // [512]       f32
  const float* wq    = (const float*)d_in[5];  // [512,512]   f32
  const float* v_v   = (const float*)d_in[6];  // [4,512]     f32
  const float* v_g   = (const float*)d_in[7];  // [4,1]       f32
  const float* r     = (const float*)d_in[8];  // [1]         f32
  float* out = (float*)d_out;                  // [4,4,64,512] f32

  f16* Kp = (f16*)d_ws;                        // 2048*512 f16 = 2 MiB
  f16* Qp = Kp + (size_t)2048 * 512;           // 256*512  f16 = 256 KiB
  f16* Wn = Qp + (size_t)256 * 512;            // 4*512    f16 = 4 KiB

  hipLaunchKernelGGL(proj_mfma, dim3(289), dim3(512), 0, stream,
                     key, query, wk, bk, wq, v_v, v_g, Kp, Qp, Wn);
  // Energy launched 4x (idempotent). Extra 3 launches are a timing probe:
  // E = (total - 26.0us)/3 attributes the proj/energy split (r12 measurement).
  for (int rep = 0; rep < 4; ++rep)
    hipLaunchKernelGGL(energy_kernel, dim3(32, 4, 4), dim3(256), 0, stream,
                       Kp, Qp, Wn, mask, r, out);
}

// Round 13
// 27.935 us; speedup vs baseline: 1.9588x; 1.9588x over previous
//
#include <hip/hip_runtime.h>
#include <math.h>

#define KLEN 512
#define QLEN 64
#define ADIM 512
#define BATCH 4
#define NH 4

typedef __attribute__((ext_vector_type(8))) short bf16x8;
typedef __attribute__((ext_vector_type(4))) float f32x4;
typedef _Float16 f16;
typedef __attribute__((ext_vector_type(2))) _Float16 f16x2;

__device__ __forceinline__ f16x2 u2h(unsigned int u) {
  union { unsigned int u; f16x2 h; } v; v.u = u; return v.h;
}

// Pack float4 -> 4 bf16 (short4) by truncation (RTZ): one v_perm_b32 per pair.
__device__ __forceinline__ short4 pack4(float4 x) {
  union { unsigned int u[2]; short4 s; } o;
  o.u[0] = __builtin_amdgcn_perm(__float_as_uint(x.y), __float_as_uint(x.x), 0x07060302);
  o.u[1] = __builtin_amdgcn_perm(__float_as_uint(x.w), __float_as_uint(x.z), 0x07060302);
  return o.s;
}

// ---------------------------------------------------------------------------
// proj_mfma v13: 577 blocks x 256 thr (2.25 blocks/CU -> cross-block TLP).
//  [0,512):  Kp tiles  m0=(bid>>4)*64, a0=(bid&15)*32
//  [512,576): Qp tiles (64 blocks)
//  576: wnorm
// Tile 64m x 32n, BK=64 (8 chunks), 4 waves as 2x2 (wave 32m x 16n, 2 accs).
// LDS dbuf (1 barrier/chunk), reg-staged loads, b128 packed writes,
// row stride 72 shorts (<=2-way bank aliasing = free).
// ---------------------------------------------------------------------------
__global__ __launch_bounds__(256) void proj_mfma(
    const float* __restrict__ key, const float* __restrict__ query,
    const float* __restrict__ wk, const float* __restrict__ bk,
    const float* __restrict__ wq,
    const float* __restrict__ v_v, const float* __restrict__ v_g,
    f16* __restrict__ Kp, f16* __restrict__ Qp, f16* __restrict__ Wn) {
  __shared__ short At[2][64 * 72];
  __shared__ short Wt[2][32 * 72];

  const int bid = blockIdx.x;
  const int tid = threadIdx.x;

  if (bid == 576) {  // ---- wnorm (256 thr, 2 elems each) ----
    __shared__ float wred[256];
    for (int h = 0; h < NH; ++h) {
      float v0 = v_v[h * ADIM + tid];
      float v1 = v_v[h * ADIM + tid + 256];
      wred[tid] = v0 * v0 + v1 * v1;
      __syncthreads();
      for (int s2 = 128; s2 > 0; s2 >>= 1) {
        if (tid < s2) wred[tid] += wred[tid + s2];
        __syncthreads();
      }
      float scale = v_g[h] / sqrtf(wred[0]);
      Wn[h * ADIM + tid] = (f16)(v0 * scale);
      Wn[h * ADIM + tid + 256] = (f16)(v1 * scale);
      __syncthreads();
    }
    return;
  }

  const float *A, *W, *bias;
  f16* C;
  int m0, a0;
  if (bid < 512) {
    A = key; W = wk; bias = bk; C = Kp;
    m0 = (bid >> 4) * 64; a0 = (bid & 15) * 32;
  } else {
    const int t = bid - 512;
    A = query; W = wq; bias = nullptr; C = Qp;
    m0 = (t >> 4) * 64; a0 = (t & 15) * 32;
  }

  const int wave = tid >> 6;
  const int wr = wave >> 1;       // 0..1: 32 m-rows
  const int wc = wave & 1;        // 0..1: 16 n-cols
  const int lane = tid & 63;
  const int lr = lane & 15, hi = lane >> 4;

  // staging maps (f32 cols within the BK=64 chunk)
  const int arow = tid >> 2, acol = (tid & 3) * 16;   // A: 4 float4/thread
  const int wrow = tid >> 3, wcol = (tid & 7) * 8;    // W: 2 float4/thread

  const float* Ab = &A[(size_t)(m0 + arow) * ADIM + acol];
  const float* Wb = &W[(size_t)(a0 + wrow) * ADIM + wcol];

  f32x4 acc0 = {0.f, 0.f, 0.f, 0.f};   // mi=0
  f32x4 acc1 = {0.f, 0.f, 0.f, 0.f};   // mi=1

  float4 a4[4], w4[2];
#pragma unroll
  for (int j = 0; j < 4; ++j) a4[j] = *(const float4*)&Ab[j * 4];
#pragma unroll
  for (int j = 0; j < 2; ++j) w4[j] = *(const float4*)&Wb[j * 4];
  {  // prologue: write chunk 0 -> buf 0
    short4 p0 = pack4(a4[0]), p1 = pack4(a4[1]), p2 = pack4(a4[2]), p3 = pack4(a4[3]);
    *(short4*)&At[0][arow * 72 + acol] = p0;
    *(short4*)&At[0][arow * 72 + acol + 4] = p1;
    *(short4*)&At[0][arow * 72 + acol + 8] = p2;
    *(short4*)&At[0][arow * 72 + acol + 12] = p3;
    short4 q0 = pack4(w4[0]), q1 = pack4(w4[1]);
    *(short4*)&Wt[0][wrow * 72 + wcol] = q0;
    *(short4*)&Wt[0][wrow * 72 + wcol + 4] = q1;
  }
  __syncthreads();

  for (int c = 0; c < 8; ++c) {
    if (c < 7) {  // issue next-chunk loads (hide under MFMA + LDS reads)
      const int base = (c + 1) * 64;
#pragma unroll
      for (int j = 0; j < 4; ++j) a4[j] = *(const float4*)&Ab[base + j * 4];
#pragma unroll
      for (int j = 0; j < 2; ++j) w4[j] = *(const float4*)&Wb[base + j * 4];
    }
    const short* Abuf = At[c & 1];
    const short* Wbuf = Wt[c & 1];
#pragma unroll
    for (int kk = 0; kk < 2; ++kk) {
      bf16x8 wf = *(const bf16x8*)&Wbuf[(wc * 16 + lr) * 72 + kk * 32 + hi * 8];
      bf16x8 af0 = *(const bf16x8*)&Abuf[(wr * 32 + lr) * 72 + kk * 32 + hi * 8];
      bf16x8 af1 = *(const bf16x8*)&Abuf[(wr * 32 + 16 + lr) * 72 + kk * 32 + hi * 8];
      acc0 = __builtin_amdgcn_mfma_f32_16x16x32_bf16(af0, wf, acc0, 0, 0, 0);
      acc1 = __builtin_amdgcn_mfma_f32_16x16x32_bf16(af1, wf, acc1, 0, 0, 0);
    }
    if (c < 7) {  // write buf^1 (its readers were fenced by previous barrier)
      const int nb = (c + 1) & 1;
      short4 p0 = pack4(a4[0]), p1 = pack4(a4[1]), p2 = pack4(a4[2]), p3 = pack4(a4[3]);
      *(short4*)&At[nb][arow * 72 + acol] = p0;
      *(short4*)&At[nb][arow * 72 + acol + 4] = p1;
      *(short4*)&At[nb][arow * 72 + acol + 8] = p2;
      *(short4*)&At[nb][arow * 72 + acol + 12] = p3;
      short4 q0 = pack4(w4[0]), q1 = pack4(w4[1]);
      *(short4*)&Wt[nb][wrow * 72 + wcol] = q0;
      *(short4*)&Wt[nb][wrow * 72 + wcol + 4] = q1;
    }
    __syncthreads();
  }

  // C layout (m89-verified): col = lane&15, row = (lane>>4)*4 + reg
  const int ccol = a0 + wc * 16 + lr;
  const float bv = bias ? bias[ccol] : 0.f;
#pragma unroll
  for (int i = 0; i < 4; ++i) {
    const int crow = m0 + wr * 32 + hi * 4 + i;
    C[(size_t)crow * ADIM + ccol] = (f16)(acc0[i] + bv);
    C[(size_t)(crow + 16) * ADIM + ccol] = (f16)(acc1[i] + bv);
  }
}

// ---------------------------------------------------------------------------
// energy — BYTE-IDENTICAL to round 10 (single launch; measured ~8-9.6 us).
// ---------------------------------------------------------------------------
__global__ __launch_bounds__(256) void energy_kernel(
    const f16* __restrict__ Kp, const f16* __restrict__ Qp,
    const f16* __restrict__ Wn, const int* __restrict__ mask,
    const float* __restrict__ r, float* __restrict__ out) {
  __shared__ f16 Kl[16 * 520];
  __shared__ f16 Ql[16 * 520];
  __shared__ float Red[2][1280];  // [wavepair][cell*5 + n]

  const int b = blockIdx.z;
  const int q0 = blockIdx.y * 16;
  const int kl0 = blockIdx.x * 16;
  const int tid = threadIdx.x;
  const int wave = tid >> 6;
  const int lane = tid & 63;
  const int klg = lane & 7;
  const int qg = lane >> 3;

  const float rv = r[0];

  const unsigned short* Kb = (const unsigned short*)(Kp + ((size_t)b * KLEN + kl0) * ADIM);
  const unsigned short* Qb = (const unsigned short*)(Qp + ((size_t)b * QLEN + q0) * ADIM);

  const unsigned int* Wd = (const unsigned int*)Wn;  // [4][256] dwords
  uint4 wreg = *(const uint4*)&Wd[(lane >> 4) * 256 + wave * 64 + (lane & 15) * 4];

#pragma unroll
  for (int j = 0; j < 4; ++j) {
    const int u = tid + 256 * j;
    const int row = u >> 6, c8 = (u & 63) * 8;
    *(uint4*)&Kl[row * 520 + c8] = *(const uint4*)&Kb[row * ADIM + c8];
    *(uint4*)&Ql[row * 520 + c8] = *(const uint4*)&Qb[row * ADIM + c8];
  }
  __syncthreads();

  float acc[2][2][4] = {};  // [kl-half][q-half][n]
  const int abase = wave * 128;

#pragma unroll
  for (int s = 0; s < 16; ++s) {
    const int off = abase + s * 8;
    uint4 ka = *(const uint4*)&Kl[klg * 520 + off];
    uint4 kb = *(const uint4*)&Kl[(klg + 8) * 520 + off];
    uint4 qa = *(const uint4*)&Ql[qg * 520 + off];
    uint4 qb = *(const uint4*)&Ql[(qg + 8) * 520 + off];
    unsigned wdw[4][4];
#pragma unroll
    for (int n = 0; n < 4; ++n) {
      wdw[n][0] = (unsigned)__builtin_amdgcn_readlane((int)wreg.x, n * 16 + s);
      wdw[n][1] = (unsigned)__builtin_amdgcn_readlane((int)wreg.y, n * 16 + s);
      wdw[n][2] = (unsigned)__builtin_amdgcn_readlane((int)wreg.z, n * 16 + s);
      wdw[n][3] = (unsigned)__builtin_amdgcn_readlane((int)wreg.w, n * 16 + s);
    }
    unsigned ks[2][4] = {{ka.x, ka.y, ka.z, ka.w}, {kb.x, kb.y, kb.z, kb.w}};
    unsigned qs[2][4] = {{qa.x, qa.y, qa.z, qa.w}, {qb.x, qb.y, qb.z, qb.w}};
#pragma unroll
    for (int j = 0; j < 4; ++j) {
      const f16x2 wv0 = u2h(wdw[0][j]), wv1 = u2h(wdw[1][j]);
      const f16x2 wv2 = u2h(wdw[2][j]), wv3 = u2h(wdw[3][j]);
#pragma unroll
      for (int ki = 0; ki < 2; ++ki) {
        const f16x2 kv = u2h(ks[ki][j]);
#pragma unroll
        for (int qi = 0; qi < 2; ++qi) {
          f16x2 sum = kv + u2h(qs[qi][j]);
          f16x2 rl = __builtin_elementwise_max(sum, (f16x2)(_Float16)0);
          acc[ki][qi][0] = __builtin_amdgcn_fdot2(rl, wv0, acc[ki][qi][0], false);
          acc[ki][qi][1] = __builtin_amdgcn_fdot2(rl, wv1, acc[ki][qi][1], false);
          acc[ki][qi][2] = __builtin_amdgcn_fdot2(rl, wv2, acc[ki][qi][2], false);
          acc[ki][qi][3] = __builtin_amdgcn_fdot2(rl, wv3, acc[ki][qi][3], false);
        }
      }
    }
  }

  const int half = wave & 1;
  if (wave < 2) {
#pragma unroll
    for (int ki = 0; ki < 2; ++ki)
#pragma unroll
      for (int qi = 0; qi < 2; ++qi) {
        const int cell = (qg + 8 * qi) * 16 + klg + 8 * ki;
#pragma unroll
        for (int n = 0; n < 4; ++n) Red[half][cell * 5 + n] = acc[ki][qi][n];
      }
  }
  __syncthreads();
  if (wave >= 2) {
#pragma unroll
    for (int ki = 0; ki < 2; ++ki)
#pragma unroll
      for (int qi = 0; qi < 2; ++qi) {
        const int cell = (qg + 8 * qi) * 16 + klg + 8 * ki;
#pragma unroll
        for (int n = 0; n < 4; ++n) Red[half][cell * 5 + n] += acc[ki][qi][n];
      }
  }
  __syncthreads();

  const float NEG_BIG = __uint_as_float(0xFF7F0000u);  // finite under bf16 cast
  const int n = tid >> 6;
  const int q = (tid >> 2) & 15;
  const int klb = (tid & 3) * 4;
  const int4 mv = *(const int4*)&mask[((size_t)b * QLEN + q0 + q) * KLEN + kl0 + klb];
  const int mm[4] = {mv.x, mv.y, mv.z, mv.w};
  float4 o;
  float* op = &o.x;
#pragma unroll
  for (int t = 0; t < 4; ++t) {
    const int cell = q * 16 + klb + t;
    float v = Red[0][cell * 5 + n] + Red[1][cell * 5 + n] + rv;
    op[t] = mm[t] ? v : NEG_BIG;
  }
  *(float4*)&out[(((size_t)b * NH + n) * QLEN + q0 + q) * KLEN + kl0 + klb] = o;
}

extern "C" void kernel_launch(void* const* d_in, const int* in_sizes, int n_in,
                              void* d_out, int out_size, void* d_ws, size_t ws_size,
                              hipStream_t stream) {
  const float* key   = (const float*)d_in[0];  // [4,512,512] f32
  const float* query = (const float*)d_in[1];  // [4,64,512]  f32
  const int*   mask  = (const int*)d_in[2];    // [4,64,512]  i32
  const float* wk    = (const float*)d_in[3];  // [512,512]   f32
  const float* bk    = (const float*)d_in[4];  // [512]       f32
  const float* wq    = (const float*)d_in[5];  // [512,512]   f32
  const float* v_v   = (const float*)d_in[6];  // [4,512]     f32
  const float* v_g   = (const float*)d_in[7];  // [4,1]       f32
  const float* r     = (const float*)d_in[8];  // [1]         f32
  float* out = (float*)d_out;                  // [4,4,64,512] f32

  f16* Kp = (f16*)d_ws;                        // 2048*512 f16 = 2 MiB
  f16* Qp = Kp + (size_t)2048 * 512;           // 256*512  f16 = 256 KiB
  f16* Wn = Qp + (size_t)256 * 512;            // 4*512    f16 = 4 KiB

  hipLaunchKernelGGL(proj_mfma, dim3(577), dim3(256), 0, stream,
                     key, query, wk, bk, wq, v_v, v_g, Kp, Qp, Wn);
  hipLaunchKernelGGL(energy_kernel, dim3(32, 4, 4), dim3(256), 0, stream,
                     Kp, Qp, Wn, mask, r, out);
}

// Round 14
// 24.301 us; speedup vs baseline: 2.2517x; 1.1495x over previous
//
#include <hip/hip_runtime.h>
#include <math.h>

#define KLEN 512
#define QLEN 64
#define ADIM 512
#define BATCH 4
#define NH 4

typedef __attribute__((ext_vector_type(8))) short bf16x8;
typedef __attribute__((ext_vector_type(4))) float f32x4;
typedef _Float16 f16;
typedef __attribute__((ext_vector_type(2))) _Float16 f16x2;

__device__ __forceinline__ f16x2 u2h(unsigned int u) {
  union { unsigned int u; f16x2 h; } v; v.u = u; return v.h;
}

// Pack float4 -> 4 bf16 (short4) by truncation (RTZ): one v_perm_b32 per pair.
__device__ __forceinline__ short4 pack4(float4 x) {
  union { unsigned int u[2]; short4 s; } o;
  o.u[0] = __builtin_amdgcn_perm(__float_as_uint(x.y), __float_as_uint(x.x), 0x07060302);
  o.u[1] = __builtin_amdgcn_perm(__float_as_uint(x.w), __float_as_uint(x.z), 0x07060302);
  return o.s;
}

// ---------------------------------------------------------------------------
// proj_mfma v14 = r7 geometry (32x32 tile, 1153 blocks -> 4.5 blocks/CU TLP,
// the measured-fastest proj config) minus r7's overheads:
//   f2bf 5-op chain -> pack4 (2 v_perm), 2 barriers/chunk -> 1 (LDS dbuf).
//  [0,1024):   Kp tiles  m0=(bid>>4)*32, a0=(bid&15)*32
//  [1024,1152): Qp tiles
//  1152: wnorm
// 4 waves as 2x2 (one 16x16x32 MFMA acc each), BK=32, 16 chunks.
// ---------------------------------------------------------------------------
__global__ __launch_bounds__(256) void proj_mfma(
    const float* __restrict__ key, const float* __restrict__ query,
    const float* __restrict__ wk, const float* __restrict__ bk,
    const float* __restrict__ wq,
    const float* __restrict__ v_v, const float* __restrict__ v_g,
    f16* __restrict__ Kp, f16* __restrict__ Qp, f16* __restrict__ Wn) {
  __shared__ short At[2][32 * 40];
  __shared__ short Wt[2][32 * 40];

  const int bid = blockIdx.x;
  const int tid = threadIdx.x;

  if (bid == 1152) {  // ---- wnorm ----
    __shared__ float wred[256];
    for (int h = 0; h < NH; ++h) {
      float v0 = v_v[h * ADIM + tid];
      float v1 = v_v[h * ADIM + tid + 256];
      wred[tid] = v0 * v0 + v1 * v1;
      __syncthreads();
      for (int s2 = 128; s2 > 0; s2 >>= 1) {
        if (tid < s2) wred[tid] += wred[tid + s2];
        __syncthreads();
      }
      float scale = v_g[h] / sqrtf(wred[0]);
      Wn[h * ADIM + tid] = (f16)(v0 * scale);
      Wn[h * ADIM + tid + 256] = (f16)(v1 * scale);
      __syncthreads();
    }
    return;
  }

  const float *A, *W, *bias;
  f16* C;
  int m0, a0;
  if (bid < 1024) {
    A = key; W = wk; bias = bk; C = Kp;
    m0 = (bid >> 4) * 32; a0 = (bid & 15) * 32;
  } else {
    const int t = bid - 1024;
    A = query; W = wq; bias = nullptr; C = Qp;
    m0 = (t >> 4) * 32; a0 = (t & 15) * 32;
  }

  const int wave = tid >> 6;
  const int wr = wave >> 1;       // 0..1: m half
  const int wc = wave & 1;        // 0..1: n half
  const int lane = tid & 63;
  const int lr = lane & 15, hi = lane >> 4;

  const int srow = tid >> 3;        // staging row 0..31
  const int scol = (tid & 7) * 4;   // staging f32 col 0,4,..,28

  const float* Arow = &A[(size_t)(m0 + srow) * ADIM + scol];
  const float* Wrow = &W[(size_t)(a0 + srow) * ADIM + scol];

  f32x4 acc = {0.f, 0.f, 0.f, 0.f};

  {  // prologue: chunk 0 -> buf 0
    float4 fa = *(const float4*)&Arow[0];
    float4 fw = *(const float4*)&Wrow[0];
    *(short4*)&At[0][srow * 40 + scol] = pack4(fa);
    *(short4*)&Wt[0][srow * 40 + scol] = pack4(fw);
  }
  __syncthreads();

  for (int c = 0; c < 16; ++c) {
    float4 na, nw;
    if (c < 15) {  // issue next-chunk loads early (hide under MFMA/LDS)
      na = *(const float4*)&Arow[(c + 1) * 32];
      nw = *(const float4*)&Wrow[(c + 1) * 32];
    }
    const short* Ab = At[c & 1];
    const short* Wb = Wt[c & 1];
    bf16x8 af = *(const bf16x8*)&Ab[(wr * 16 + lr) * 40 + hi * 8];
    bf16x8 wf = *(const bf16x8*)&Wb[(wc * 16 + lr) * 40 + hi * 8];
    acc = __builtin_amdgcn_mfma_f32_16x16x32_bf16(af, wf, acc, 0, 0, 0);
    if (c < 15) {  // write buf^1 (readers fenced by previous barrier)
      *(short4*)&At[(c + 1) & 1][srow * 40 + scol] = pack4(na);
      *(short4*)&Wt[(c + 1) & 1][srow * 40 + scol] = pack4(nw);
    }
    __syncthreads();
  }

  // C layout (m89-verified): col = lane&15, row = (lane>>4)*4 + reg
  const int ccol = a0 + wc * 16 + lr;
  const float bv = bias ? bias[ccol] : 0.f;
#pragma unroll
  for (int i = 0; i < 4; ++i) {
    const int crow = m0 + wr * 16 + hi * 4 + i;
    C[(size_t)crow * ADIM + ccol] = (f16)(acc[i] + bv);
  }
}

// ---------------------------------------------------------------------------
// energy — BYTE-IDENTICAL to round 10 (measured ~9.6 us incl. launch).
// ---------------------------------------------------------------------------
__global__ __launch_bounds__(256) void energy_kernel(
    const f16* __restrict__ Kp, const f16* __restrict__ Qp,
    const f16* __restrict__ Wn, const int* __restrict__ mask,
    const float* __restrict__ r, float* __restrict__ out) {
  __shared__ f16 Kl[16 * 520];
  __shared__ f16 Ql[16 * 520];
  __shared__ float Red[2][1280];  // [wavepair][cell*5 + n]

  const int b = blockIdx.z;
  const int q0 = blockIdx.y * 16;
  const int kl0 = blockIdx.x * 16;
  const int tid = threadIdx.x;
  const int wave = tid >> 6;
  const int lane = tid & 63;
  const int klg = lane & 7;
  const int qg = lane >> 3;

  const float rv = r[0];

  const unsigned short* Kb = (const unsigned short*)(Kp + ((size_t)b * KLEN + kl0) * ADIM);
  const unsigned short* Qb = (const unsigned short*)(Qp + ((size_t)b * QLEN + q0) * ADIM);

  const unsigned int* Wd = (const unsigned int*)Wn;  // [4][256] dwords
  uint4 wreg = *(const uint4*)&Wd[(lane >> 4) * 256 + wave * 64 + (lane & 15) * 4];

#pragma unroll
  for (int j = 0; j < 4; ++j) {
    const int u = tid + 256 * j;
    const int row = u >> 6, c8 = (u & 63) * 8;
    *(uint4*)&Kl[row * 520 + c8] = *(const uint4*)&Kb[row * ADIM + c8];
    *(uint4*)&Ql[row * 520 + c8] = *(const uint4*)&Qb[row * ADIM + c8];
  }
  __syncthreads();

  float acc[2][2][4] = {};  // [kl-half][q-half][n]
  const int abase = wave * 128;

#pragma unroll
  for (int s = 0; s < 16; ++s) {
    const int off = abase + s * 8;
    uint4 ka = *(const uint4*)&Kl[klg * 520 + off];
    uint4 kb = *(const uint4*)&Kl[(klg + 8) * 520 + off];
    uint4 qa = *(const uint4*)&Ql[qg * 520 + off];
    uint4 qb = *(const uint4*)&Ql[(qg + 8) * 520 + off];
    unsigned wdw[4][4];
#pragma unroll
    for (int n = 0; n < 4; ++n) {
      wdw[n][0] = (unsigned)__builtin_amdgcn_readlane((int)wreg.x, n * 16 + s);
      wdw[n][1] = (unsigned)__builtin_amdgcn_readlane((int)wreg.y, n * 16 + s);
      wdw[n][2] = (unsigned)__builtin_amdgcn_readlane((int)wreg.z, n * 16 + s);
      wdw[n][3] = (unsigned)__builtin_amdgcn_readlane((int)wreg.w, n * 16 + s);
    }
    unsigned ks[2][4] = {{ka.x, ka.y, ka.z, ka.w}, {kb.x, kb.y, kb.z, kb.w}};
    unsigned qs[2][4] = {{qa.x, qa.y, qa.z, qa.w}, {qb.x, qb.y, qb.z, qb.w}};
#pragma unroll
    for (int j = 0; j < 4; ++j) {
      const f16x2 wv0 = u2h(wdw[0][j]), wv1 = u2h(wdw[1][j]);
      const f16x2 wv2 = u2h(wdw[2][j]), wv3 = u2h(wdw[3][j]);
#pragma unroll
      for (int ki = 0; ki < 2; ++ki) {
        const f16x2 kv = u2h(ks[ki][j]);
#pragma unroll
        for (int qi = 0; qi < 2; ++qi) {
          f16x2 sum = kv + u2h(qs[qi][j]);
          f16x2 rl = __builtin_elementwise_max(sum, (f16x2)(_Float16)0);
          acc[ki][qi][0] = __builtin_amdgcn_fdot2(rl, wv0, acc[ki][qi][0], false);
          acc[ki][qi][1] = __builtin_amdgcn_fdot2(rl, wv1, acc[ki][qi][1], false);
          acc[ki][qi][2] = __builtin_amdgcn_fdot2(rl, wv2, acc[ki][qi][2], false);
          acc[ki][qi][3] = __builtin_amdgcn_fdot2(rl, wv3, acc[ki][qi][3], false);
        }
      }
    }
  }

  const int half = wave & 1;
  if (wave < 2) {
#pragma unroll
    for (int ki = 0; ki < 2; ++ki)
#pragma unroll
      for (int qi = 0; qi < 2; ++qi) {
        const int cell = (qg + 8 * qi) * 16 + klg + 8 * ki;
#pragma unroll
        for (int n = 0; n < 4; ++n) Red[half][cell * 5 + n] = acc[ki][qi][n];
      }
  }
  __syncthreads();
  if (wave >= 2) {
#pragma unroll
    for (int ki = 0; ki < 2; ++ki)
#pragma unroll
      for (int qi = 0; qi < 2; ++qi) {
        const int cell = (qg + 8 * qi) * 16 + klg + 8 * ki;
#pragma unroll
        for (int n = 0; n < 4; ++n) Red[half][cell * 5 + n] += acc[ki][qi][n];
      }
  }
  __syncthreads();

  const float NEG_BIG = __uint_as_float(0xFF7F0000u);  // finite under bf16 cast
  const int n = tid >> 6;
  const int q = (tid >> 2) & 15;
  const int klb = (tid & 3) * 4;
  const int4 mv = *(const int4*)&mask[((size_t)b * QLEN + q0 + q) * KLEN + kl0 + klb];
  const int mm[4] = {mv.x, mv.y, mv.z, mv.w};
  float4 o;
  float* op = &o.x;
#pragma unroll
  for (int t = 0; t < 4; ++t) {
    const int cell = q * 16 + klb + t;
    float v = Red[0][cell * 5 + n] + Red[1][cell * 5 + n] + rv;
    op[t] = mm[t] ? v : NEG_BIG;
  }
  *(float4*)&out[(((size_t)b * NH + n) * QLEN + q0 + q) * KLEN + kl0 + klb] = o;
}

extern "C" void kernel_launch(void* const* d_in, const int* in_sizes, int n_in,
                              void* d_out, int out_size, void* d_ws, size_t ws_size,
                              hipStream_t stream) {
  const float* key   = (const float*)d_in[0];  // [4,512,512] f32
  const float* query = (const float*)d_in[1];  // [4,64,512]  f32
  const int*   mask  = (const int*)d_in[2];    // [4,64,512]  i32
  const float* wk    = (const float*)d_in[3];  // [512,512]   f32
  const float* bk    = (const float*)d_in[4];  // [512]       f32
  const float* wq    = (const float*)d_in[5];  // [512,512]   f32
  const float* v_v   = (const float*)d_in[6];  // [4,512]     f32
  const float* v_g   = (const float*)d_in[7];  // [4,1]       f32
  const float* r     = (const float*)d_in[8];  // [1]         f32
  float* out = (float*)d_out;                  // [4,4,64,512] f32

  f16* Kp = (f16*)d_ws;                        // 2048*512 f16 = 2 MiB
  f16* Qp = Kp + (size_t)2048 * 512;           // 256*512  f16 = 256 KiB
  f16* Wn = Qp + (size_t)256 * 512;            // 4*512    f16 = 4 KiB

  hipLaunchKernelGGL(proj_mfma, dim3(1153), dim3(256), 0, stream,
                     key, query, wk, bk, wq, v_v, v_g, Kp, Qp, Wn);
  hipLaunchKernelGGL(energy_kernel, dim3(32, 4, 4), dim3(256), 0, stream,
                     Kp, Qp, Wn, mask, r, out);
}